// Round 5
// baseline (16.903 us; speedup 1.0000x reference)
//
#include <hip/hip_runtime.h>

// ImplicitComplexModalFilter: K[h][l] = 2*Re[ sum_n Cm[h,n] * exp(dtA[h,n]*l) ]
// H=1024, N=64, L=2048, channels=1, n_ssm=H (rep=1).
//
// Round 5: split L across 2 blocks per h (grid 2048, LPT=16) to halve acc
// register pressure (32 VGPR) and double wave count -> more latency hiding.
// 4 waves/block each own 16 n's; lanes own l0 = l_base + lane, stride 64.
// Real 2-term packed recurrence y_j = p*y_{j-1} + q*y_{j-2} in v2f
// (v_pk_{mul,fma,add}_f32). Cross-wave partials via 16KB LDS, float4 epilogue.

typedef float v2f __attribute__((ext_vector_type(2)));

#define Hdim   1024
#define Ndim   64
#define Ldim   2048
#define BLK    256
#define LANES  64
#define LPT    16                  // l-values per lane, strided by LANES
#define LCHUNK (LANES * LPT)       // 1024 l's per block
#define NPW    16                  // n's per wave
#define WAVES  4

__global__ __launch_bounds__(BLK, 4) void icmf_kernel(
    const float* __restrict__ log_dt,
    const float* __restrict__ C_re, const float* __restrict__ C_im,
    const float* __restrict__ B_re, const float* __restrict__ B_im,
    const float* __restrict__ inv_A_real, const float* __restrict__ A_imag,
    float* __restrict__ out)
{
    __shared__ __align__(16) float4 s_seed[Ndim];  // {ar2, airev, 2*cmre, 2*cmim}
    __shared__ __align__(16) float2 s_w[Ndim];     // {wr, wi}
    __shared__ __align__(16) float  s_p[Ndim];     // 2*wr
    __shared__ __align__(16) float  s_q[Ndim];     // -|w|^2
    __shared__ __align__(16) float  s_red[WAVES][LCHUNK];  // 16 KB partials

    const int h      = blockIdx.x >> 1;
    const int l_base = (blockIdx.x & 1) * LCHUNK;
    const int tid    = threadIdx.x;
    const int wave   = tid >> 6;
    const int lane   = tid & 63;

    if (tid < Ndim) {
        const int n   = tid;
        const int idx = h * Ndim + n;
        const float dt  = expf(log_dt[h]);
        const float Are = -expf(inv_A_real[idx]);
        const float Aim = A_imag[idx];
        const float ar  = dt * Are;          // Re(dtA) < 0
        const float ai  = dt * Aim;          // Im(dtA)
        // scale = dt / (1 - dtA/2)
        const float dre = 1.0f - 0.5f * ar;
        const float dim = -0.5f * ai;
        const float k   = dt / (dre * dre + dim * dim);
        const float sre =  dre * k;
        const float sim = -dim * k;
        // B*C (complex)
        const float br = B_re[idx], bi = B_im[idx];
        const float cr = C_re[idx], ci = C_im[idx];
        const float bcr = br * cr - bi * ci;
        const float bci = br * ci + bi * cr;
        const float cmre = 2.0f * (bcr * sre - bci * sim);  // fold final 2x
        const float cmim = 2.0f * (bcr * sim + bci * sre);
        const float ar2   = ar * 1.4426950408889634f;   // log2(e)
        const float airev = ai * 0.15915494309189535f;  // 1/(2*pi): revolutions
        // w = exp(dtA * LANES): stride-64 advance, |w| = e <= 1
        const float e  = __builtin_amdgcn_exp2f(ar2 * (float)LANES);
        const float r  = airev * (float)LANES;
        const float rf = r - floorf(r);
        const float wr = e * __builtin_amdgcn_cosf(rf);
        const float wi = e * __builtin_amdgcn_sinf(rf);
        s_seed[n] = make_float4(ar2, airev, cmre, cmim);
        s_w[n]    = make_float2(wr, wi);
        s_p[n]    = 2.0f * wr;
        s_q[n]    = -(e * e);
    }
    __syncthreads();

    v2f acc[LPT];
#pragma unroll
    for (int j = 0; j < LPT; ++j) acc[j] = (v2f)(0.0f);

    const float l0    = (float)(l_base + lane);
    const int   nbase = wave * NPW;

#pragma unroll
    for (int g = 0; g < NPW; g += 4) {   // 4 chains = 2 packed pairs per group
        const int n0 = nbase + g;
        // ---- scalar seeds: y0 = Re(Cm z^l0), y1 = Re(Cm z^(l0+64)) ----
        float y0[4], y1[4];
#pragma unroll
        for (int k = 0; k < 4; ++k) {
            const float4 sd = s_seed[n0 + k];
            const float2 w  = s_w[n0 + k];
            const float e0 = __builtin_amdgcn_exp2f(sd.x * l0);
            float f = sd.y * l0;
            f -= floorf(f);
            const float zr = e0 * __builtin_amdgcn_cosf(f);
            const float zi = e0 * __builtin_amdgcn_sinf(f);
            const float u0r = sd.z * zr - sd.w * zi;   // Re(Cm z0)
            const float u0i = sd.z * zi + sd.w * zr;   // Im(Cm z0)
            y0[k] = u0r;
            y1[k] = u0r * w.x - u0i * w.y;             // Re(Cm z0 w)
        }
        // ---- pack 2 pairs ----
        const v2f P0 = *(const v2f*)&s_p[n0];
        const v2f P1 = *(const v2f*)&s_p[n0 + 2];
        const v2f Q0 = *(const v2f*)&s_q[n0];
        const v2f Q1 = *(const v2f*)&s_q[n0 + 2];
        v2f Ya2, Yb2, Ya1, Yb1;
        Ya2.x = y0[0]; Ya2.y = y0[1];
        Yb2.x = y0[2]; Yb2.y = y0[3];
        Ya1.x = y1[0]; Ya1.y = y1[1];
        Yb1.x = y1[2]; Yb1.y = y1[3];
        acc[0] += Ya2; acc[0] += Yb2;
        acc[1] += Ya1; acc[1] += Yb1;
        // ---- packed 2-term recurrence: 3 pk-ops per pair per j ----
#pragma unroll
        for (int j = 2; j < LPT; ++j) {
            const v2f t0 = Q0 * Ya2;
            const v2f ya = __builtin_elementwise_fma(P0, Ya1, t0);
            acc[j] += ya;
            Ya2 = Ya1; Ya1 = ya;
            const v2f t1 = Q1 * Yb2;
            const v2f yb = __builtin_elementwise_fma(P1, Yb1, t1);
            acc[j] += yb;
            Yb2 = Yb1; Yb1 = yb;
        }
    }

    // ---- cross-wave reduction over the 4 n-groups ----
    {
        float* dst = &s_red[wave][lane];
#pragma unroll
        for (int j = 0; j < LPT; ++j) dst[j * LANES] = acc[j].x + acc[j].y;
    }
    __syncthreads();

    // ---- float4 epilogue: 4 contiguous l's per thread ----
    {
        const float4* r0 = (const float4*)&s_red[0][0];
        const float4* r1 = (const float4*)&s_red[1][0];
        const float4* r2 = (const float4*)&s_red[2][0];
        const float4* r3 = (const float4*)&s_red[3][0];
        const float4 a = r0[tid];
        const float4 b = r1[tid];
        const float4 c = r2[tid];
        const float4 d = r3[tid];
        float4 v;
        v.x = (a.x + b.x) + (c.x + d.x);
        v.y = (a.y + b.y) + (c.y + d.y);
        v.z = (a.z + b.z) + (c.z + d.z);
        v.w = (a.w + b.w) + (c.w + d.w);
        ((float4*)(out + h * Ldim + l_base))[tid] = v;
    }
}

extern "C" void kernel_launch(void* const* d_in, const int* in_sizes, int n_in,
                              void* d_out, int out_size, void* d_ws, size_t ws_size,
                              hipStream_t stream) {
    // d_in order: L(scalar), log_dt, C_re, C_im, B_re, B_im, inv_A_real, A_imag
    const float* log_dt     = (const float*)d_in[1];
    const float* C_re       = (const float*)d_in[2];
    const float* C_im       = (const float*)d_in[3];
    const float* B_re       = (const float*)d_in[4];
    const float* B_im       = (const float*)d_in[5];
    const float* inv_A_real = (const float*)d_in[6];
    const float* A_imag     = (const float*)d_in[7];
    float* out = (float*)d_out;

    icmf_kernel<<<Hdim * (Ldim / LCHUNK), BLK, 0, stream>>>(
        log_dt, C_re, C_im, B_re, B_im, inv_A_real, A_imag, out);
}

// Round 6
// 14.737 us; speedup vs baseline: 1.1470x; 1.1470x over previous
//
#include <hip/hip_runtime.h>
#include <hip/hip_bf16.h>

// ImplicitComplexModalFilter via MFMA factorization.
// K[h, 32a+b] = Re( sum_n U[a,n] * V[n,b] ),  U[a,n] = Cm_n * z_n^(32a)  (64x64),
// V[n,b] = z_n^b (64x32), z_n = exp(dtA_n).  Per h: two real matmuls
// (Ur Vr - Ui Vi), each bf16 hi/lo compensated (3 segments) -> 6 K=64 segments.
// One h per 128-thread block (2 waves); MFMA 16x16x32 bf16 (verified layouts).

typedef __attribute__((ext_vector_type(8))) short bf16x8;
typedef __attribute__((ext_vector_type(4))) short s16x4;
typedef __attribute__((ext_vector_type(4))) float f32x4;

#define Hdim 1024
#define Ndim 64
#define Ldim 2048
#define NPAD 68   // padded row stride (ushort units): 136B -> 2-way bank alias (free)

__device__ __forceinline__ void cmul(float& xr, float& xi, float yr, float yi) {
    const float tr = xr * yr - xi * yi;
    xi = xr * yi + xi * yr;
    xr = tr;
}

__device__ __forceinline__ ushort bf16_bits(float x) {
    __hip_bfloat16 h = __float2bfloat16(x);
    return *reinterpret_cast<ushort*>(&h);
}
__device__ __forceinline__ float bf16_val(ushort b) {
    __hip_bfloat16 h;
    *reinterpret_cast<ushort*>(&h) = b;
    return __bfloat162float(h);
}
__device__ __forceinline__ void store_split(float x, ushort* ph, ushort* pl) {
    const ushort hb = bf16_bits(x);
    *ph = hb;
    *pl = bf16_bits(x - bf16_val(hb));
}
__device__ __forceinline__ bf16x8 load_frag(const ushort* p) {
    const s16x4 a = *(const s16x4*)p;
    const s16x4 b = *(const s16x4*)(p + 4);
    bf16x8 f;
    f[0] = a[0]; f[1] = a[1]; f[2] = a[2]; f[3] = a[3];
    f[4] = b[0]; f[5] = b[1]; f[6] = b[2]; f[7] = b[3];
    return f;
}

__global__ __launch_bounds__(128) void icmf_mfma(
    const float* __restrict__ log_dt,
    const float* __restrict__ C_re, const float* __restrict__ C_im,
    const float* __restrict__ B_re, const float* __restrict__ B_im,
    const float* __restrict__ inv_A_real, const float* __restrict__ A_imag,
    float* __restrict__ out)
{
    // A matrices [a][n]: real hi/lo, NEGATED imag hi/lo. B^T matrices [b][n].
    __shared__ ushort sArh[64][NPAD], sArl[64][NPAD], sAih[64][NPAD], sAil[64][NPAD];
    __shared__ ushort sBrh[32][NPAD], sBrl[32][NPAD], sBih[32][NPAD], sBil[32][NPAD];

    const int h   = blockIdx.x;
    const int tid = threadIdx.x;
    const int n   = tid & 63;   // lane within wave = state index n
    const int g   = tid >> 6;   // wave id: 0/1

    // ---- per-n scalar setup (duplicated across the 2 waves) ----
    {
        const int idx = h * Ndim + n;
        const float dt = expf(log_dt[h]);
        const float ar = -dt * expf(inv_A_real[idx]);   // Re(dtA) < 0
        const float ai =  dt * A_imag[idx];             // Im(dtA)
        // scale = dt / (1 - dtA/2)
        const float dre = 1.0f - 0.5f * ar;
        const float dim = -0.5f * ai;
        const float kk  = dt / (dre * dre + dim * dim);
        const float sre =  dre * kk;
        const float sim = -dim * kk;
        const float br = B_re[idx], bi = B_im[idx];
        const float cr = C_re[idx], ci = C_im[idx];
        const float bcr = br * cr - bi * ci;
        const float bci = br * ci + bi * cr;
        float cmr = 2.0f * (bcr * sre - bci * sim);     // fold final 2x
        float cmi = 2.0f * (bcr * sim + bci * sre);
        // z = exp(dtA)
        const float er  = __builtin_amdgcn_exp2f(ar * 1.4426950408889634f);
        float rev = ai * 0.15915494309189535f;
        rev -= floorf(rev);
        const float zr = er * __builtin_amdgcn_cosf(rev);
        const float zi = er * __builtin_amdgcn_sinf(rev);
        // powers: z^16, z^32, z^512, z^1024
        float z16r = zr, z16i = zi;
        for (int s = 0; s < 4; ++s) cmul(z16r, z16i, z16r, z16i);
        float z32r = z16r, z32i = z16i;
        cmul(z32r, z32i, z32r, z32i);
        float w512r = z32r, w512i = z32i;
        for (int s = 0; s < 4; ++s) cmul(w512r, w512i, w512r, w512i);
        float w1kr = w512r, w1ki = w512i;
        cmul(w1kr, w1ki, w512r, w512i);                 // z^1024

        // ---- U-gen: this wave owns quarters q = g and q = g+2 ----
        float uar = cmr, uai = cmi;
        if (g) cmul(uar, uai, w512r, w512i);            // q = 1 start: Cm z^512
        float ubr = uar, ubi = uai;
        cmul(ubr, ubi, w1kr, w1ki);                     // q = g+2 start
#pragma unroll
        for (int s = 0; s < 16; ++s) {
            const int a0 = 16 * g + s;
            const int a1 = 16 * (g + 2) + s;
            store_split(uar,  &sArh[a0][n], &sArl[a0][n]);
            store_split(-uai, &sAih[a0][n], &sAil[a0][n]);
            store_split(ubr,  &sArh[a1][n], &sArl[a1][n]);
            store_split(-ubi, &sAih[a1][n], &sAil[a1][n]);
            cmul(uar, uai, z32r, z32i);
            cmul(ubr, ubi, z32r, z32i);
        }
        // ---- V-gen: wave g owns b in [16g, 16g+16) ----
        float vr = 1.0f, vi = 0.0f;
        if (g) { vr = z16r; vi = z16i; }
#pragma unroll
        for (int s = 0; s < 16; ++s) {
            const int b = 16 * g + s;
            store_split(vr, &sBrh[b][n], &sBrl[b][n]);
            store_split(vi, &sBih[b][n], &sBil[b][n]);
            cmul(vr, vi, zr, zi);
        }
    }
    __syncthreads();

    // ---- MFMA phase: wave g owns a-tiles {2g, 2g+1} (rows 32g .. 32g+31) ----
    const int lane = tid & 63;
    const int mrow = lane & 15;
    const int kgrp = lane >> 4;

    f32x4 acc00 = {0.f, 0.f, 0.f, 0.f};
    f32x4 acc01 = {0.f, 0.f, 0.f, 0.f};
    f32x4 acc10 = {0.f, 0.f, 0.f, 0.f};
    f32x4 acc11 = {0.f, 0.f, 0.f, 0.f};

    const ushort* Aseg[6] = { &sArh[0][0], &sArl[0][0], &sArh[0][0],
                              &sAih[0][0], &sAil[0][0], &sAih[0][0] };
    const ushort* Bseg[6] = { &sBrh[0][0], &sBrh[0][0], &sBrl[0][0],
                              &sBih[0][0], &sBih[0][0], &sBil[0][0] };

#pragma unroll
    for (int s = 0; s < 6; ++s) {
        const ushort* Am = Aseg[s];
        const ushort* Bm = Bseg[s];
#pragma unroll
        for (int ks = 0; ks < 2; ++ks) {
            const int n0 = 32 * ks + kgrp * 8;          // 8 consecutive k per lane
            const bf16x8 afa = load_frag(Am + (32 * g + mrow) * NPAD + n0);
            const bf16x8 afb = load_frag(Am + (32 * g + 16 + mrow) * NPAD + n0);
            const bf16x8 bf0 = load_frag(Bm + mrow * NPAD + n0);
            const bf16x8 bf1 = load_frag(Bm + (16 + mrow) * NPAD + n0);
            acc00 = __builtin_amdgcn_mfma_f32_16x16x32_bf16(afa, bf0, acc00, 0, 0, 0);
            acc01 = __builtin_amdgcn_mfma_f32_16x16x32_bf16(afa, bf1, acc01, 0, 0, 0);
            acc10 = __builtin_amdgcn_mfma_f32_16x16x32_bf16(afb, bf0, acc10, 0, 0, 0);
            acc11 = __builtin_amdgcn_mfma_f32_16x16x32_bf16(afb, bf1, acc11, 0, 0, 0);
        }
    }

    // ---- epilogue: D row = kgrp*4 + r (a_local), col = mrow (b_local) ----
    float* o = out + h * Ldim;
#pragma unroll
    for (int r = 0; r < 4; ++r) {
        const int arow = kgrp * 4 + r;
        o[(32 * g +      arow) * 32 +      mrow] = acc00[r];
        o[(32 * g +      arow) * 32 + 16 + mrow] = acc01[r];
        o[(32 * g + 16 + arow) * 32 +      mrow] = acc10[r];
        o[(32 * g + 16 + arow) * 32 + 16 + mrow] = acc11[r];
    }
}

extern "C" void kernel_launch(void* const* d_in, const int* in_sizes, int n_in,
                              void* d_out, int out_size, void* d_ws, size_t ws_size,
                              hipStream_t stream) {
    // d_in order: L(scalar), log_dt, C_re, C_im, B_re, B_im, inv_A_real, A_imag
    const float* log_dt     = (const float*)d_in[1];
    const float* C_re       = (const float*)d_in[2];
    const float* C_im       = (const float*)d_in[3];
    const float* B_re       = (const float*)d_in[4];
    const float* B_im       = (const float*)d_in[5];
    const float* inv_A_real = (const float*)d_in[6];
    const float* A_imag     = (const float*)d_in[7];
    float* out = (float*)d_out;

    icmf_mfma<<<Hdim, 128, 0, stream>>>(log_dt, C_re, C_im, B_re, B_im,
                                        inv_A_real, A_imag, out);
}

// Round 7
// 10.843 us; speedup vs baseline: 1.5588x; 1.3590x over previous
//
#include <hip/hip_runtime.h>

// ImplicitComplexModalFilter via single-segment FP16 MFMA factorization.
// K[h, 32a+b] = Re( sum_n U[a,n] * V[n,b] ),  U[a,n] = Cm_n * z_n^(32a) (64x64),
// V[n,b] = z_n^b (64x32), z_n = exp(dtA_n).
// Re(U V) = (Re U)(Re V) + (-Im U)(Im V)  ->  ONE K=128 f16 matmul:
//   A  = [Re U | -Im U]   (64 x 128)
//   B^T= [Re V ; Im V] per col -> sB[b][k]  (32 x 128)
// FP16 error budget: ~1e-3 rel/term, RSS over 64 terms ~1e-2 << 0.109 threshold.
// 256 threads = 4 waves per h; wave w gens a-rows [16w,16w+16), b-rows [8w,8w+8),
// then computes m-tile w (16x32) with 4 K-steps of mfma_f32_16x16x32_f16.

typedef __attribute__((ext_vector_type(8))) _Float16 f16x8;
typedef __attribute__((ext_vector_type(4))) float f32x4;

#define Hdim 1024
#define Ndim 64
#define Ldim 2048
#define KPAD 136   // f16 units: 272B row stride, 16B-aligned, conflict-free b128 reads

#define LOG2E 1.4426950408889634f
#define INV2PI 0.15915494309189535f

__device__ __forceinline__ void cmul(float& xr, float& xi, float yr, float yi) {
    const float tr = fmaf(xr, yr, -(xi * yi));
    xi = fmaf(xr, yi, xi * yr);
    xr = tr;
}

__global__ __launch_bounds__(256) void icmf_mfma(
    const float* __restrict__ log_dt,
    const float* __restrict__ C_re, const float* __restrict__ C_im,
    const float* __restrict__ B_re, const float* __restrict__ B_im,
    const float* __restrict__ inv_A_real, const float* __restrict__ A_imag,
    float* __restrict__ out)
{
    __shared__ __align__(16) _Float16 sA[64][KPAD];  // [a][k]: k<64 Re(U), k>=64 -Im(U)
    __shared__ __align__(16) _Float16 sB[32][KPAD];  // [b][k]: k<64 Re(V), k>=64  Im(V)

    const int h   = blockIdx.x;
    const int tid = threadIdx.x;
    const int w   = tid >> 6;   // wave 0..3
    const int n   = tid & 63;   // lane = state index n

    // ---- per-n scalar setup (each wave computes its own slice's chains) ----
    {
        const int idx = h * Ndim + n;
        const float dt = __builtin_amdgcn_exp2f(log_dt[h] * LOG2E);
        const float ar = -dt * __builtin_amdgcn_exp2f(inv_A_real[idx] * LOG2E);
        const float ai =  dt * A_imag[idx];
        // scale = dt / (1 - dtA/2)
        const float dre = 1.0f - 0.5f * ar;
        const float dim = -0.5f * ai;
        const float kk  = dt / (dre * dre + dim * dim);
        const float sre =  dre * kk;
        const float sim = -dim * kk;
        // Cm = 2 * B*C*scale (fold final 2x)
        const float br = B_re[idx], bi = B_im[idx];
        const float cr = C_re[idx], ci = C_im[idx];
        const float bcr = br * cr - bi * ci;
        const float bci = br * ci + bi * cr;
        const float cmr = 2.0f * (bcr * sre - bci * sim);
        const float cmi = 2.0f * (bcr * sim + bci * sre);
        // z = exp(dtA)
        const float er = __builtin_amdgcn_exp2f(ar * LOG2E);
        float rev = ai * INV2PI;
        rev -= floorf(rev);
        const float zr = er * __builtin_amdgcn_cosf(rev);
        const float zi = er * __builtin_amdgcn_sinf(rev);
        // power ladder: z^8, z^16, z^32, z^512
        float z8r = zr, z8i = zi;
        cmul(z8r, z8i, z8r, z8i);
        cmul(z8r, z8i, z8r, z8i);
        cmul(z8r, z8i, z8r, z8i);                       // z^8
        float z16r = z8r, z16i = z8i;
        cmul(z16r, z16i, z16r, z16i);                   // z^16
        float z32r = z16r, z32i = z16i;
        cmul(z32r, z32i, z32r, z32i);                   // z^32
        float z512r = z32r, z512i = z32i;
        for (int s = 0; s < 4; ++s) cmul(z512r, z512i, z512r, z512i);  // z^512

        // V chain start: z^(8w)
        float vr = 1.0f, vi = 0.0f;
        if (w & 1) cmul(vr, vi, z8r, z8i);
        if (w & 2) cmul(vr, vi, z16r, z16i);
        // U chain start: Cm * z^(512w)
        float ur = cmr, ui = cmi;
        if (w & 1) cmul(ur, ui, z512r, z512i);
        if (w & 2) {
            float t1r = z512r, t1i = z512i;
            cmul(t1r, t1i, z512r, z512i);               // z^1024
            cmul(ur, ui, t1r, t1i);
        }
        // V-gen: b = 8w + s
#pragma unroll
        for (int s = 0; s < 8; ++s) {
            sB[8 * w + s][n]      = (_Float16)vr;
            sB[8 * w + s][64 + n] = (_Float16)vi;
            cmul(vr, vi, zr, zi);
        }
        // U-gen: a = 16w + s (store negated imag)
#pragma unroll
        for (int s = 0; s < 16; ++s) {
            sA[16 * w + s][n]      = (_Float16)ur;
            sA[16 * w + s][64 + n] = (_Float16)(-ui);
            cmul(ur, ui, z32r, z32i);
        }
    }
    __syncthreads();

    // ---- MFMA: wave w owns m-tile w (a rows 16w..16w+16), 2 n-tiles, K=128 ----
    const int mrow = n & 15;
    const int kgrp = n >> 4;
    f32x4 acc0 = {0.f, 0.f, 0.f, 0.f};
    f32x4 acc1 = {0.f, 0.f, 0.f, 0.f};
#pragma unroll
    for (int ks = 0; ks < 4; ++ks) {
        const int k0 = ks * 32 + kgrp * 8;              // 8 consecutive k per lane
        const f16x8 af = *(const f16x8*)&sA[16 * w + mrow][k0];
        const f16x8 b0 = *(const f16x8*)&sB[mrow][k0];
        const f16x8 b1 = *(const f16x8*)&sB[16 + mrow][k0];
        acc0 = __builtin_amdgcn_mfma_f32_16x16x32_f16(af, b0, acc0, 0, 0, 0);
        acc1 = __builtin_amdgcn_mfma_f32_16x16x32_f16(af, b1, acc1, 0, 0, 0);
    }

    // ---- epilogue: D col = mrow (b), row = kgrp*4 + r (a_local) ----
    float* o = out + h * Ldim + (16 * w) * 32;
#pragma unroll
    for (int r = 0; r < 4; ++r) {
        const int arow = kgrp * 4 + r;
        o[arow * 32 + mrow]      = acc0[r];
        o[arow * 32 + 16 + mrow] = acc1[r];
    }
}

extern "C" void kernel_launch(void* const* d_in, const int* in_sizes, int n_in,
                              void* d_out, int out_size, void* d_ws, size_t ws_size,
                              hipStream_t stream) {
    // d_in order: L(scalar), log_dt, C_re, C_im, B_re, B_im, inv_A_real, A_imag
    const float* log_dt     = (const float*)d_in[1];
    const float* C_re       = (const float*)d_in[2];
    const float* C_im       = (const float*)d_in[3];
    const float* B_re       = (const float*)d_in[4];
    const float* B_im       = (const float*)d_in[5];
    const float* inv_A_real = (const float*)d_in[6];
    const float* A_imag     = (const float*)d_in[7];
    float* out = (float*)d_out;

    icmf_mfma<<<Hdim, 256, 0, stream>>>(log_dt, C_re, C_im, B_re, B_im,
                                        inv_A_real, A_imag, out);
}

// Round 9
// 10.675 us; speedup vs baseline: 1.5835x; 1.0158x over previous
//
#include <hip/hip_runtime.h>

// ImplicitComplexModalFilter via single-pass FP16 MFMA factorization.
// K[h, 32a+b] = Re( sum_n U[a,n] * V[n,b] ),  U[a,n] = Cm_n * z_n^(32a) (64x64),
// V[n,b] = z_n^b (64x32), z_n = exp(dtA_n).
// Interleaved-complex K=128 contraction: A[a][2n]=Re U, A[a][2n+1]=-Im U;
// B^T[b][2n]=Re V, B^T[b][2n+1]=Im V  ->  sum_k A B = Re(U V).
// Round 9: R8 + fix cvt_pkrtz return type (__fp16 vector, not _Float16 vector).

typedef __attribute__((ext_vector_type(8))) _Float16 f16x8;
typedef __attribute__((ext_vector_type(2))) __fp16   h16x2;  // cvt_pkrtz result type
typedef __attribute__((ext_vector_type(4))) float    f32x4;

#define Hdim 1024
#define Ndim 64
#define Ldim 2048
#define KPAD 136   // f16 units: 272B row stride, 16B-aligned, conflict-free b128
#define CPAD 36    // f32 units: 144B row stride, 16B-aligned, 2-way alias (free)

#define LOG2E  1.4426950408889634f
#define INV2PI 0.15915494309189535f

__device__ __forceinline__ void cmul(float& xr, float& xi, float yr, float yi) {
    const float tr = fmaf(xr, yr, -(xi * yi));
    xi = fmaf(xr, yi, xi * yr);
    xr = tr;
}

__global__ __launch_bounds__(512, 8) void icmf_mfma(
    const float* __restrict__ log_dt,
    const float* __restrict__ C_re, const float* __restrict__ C_im,
    const float* __restrict__ B_re, const float* __restrict__ B_im,
    const float* __restrict__ inv_A_real, const float* __restrict__ A_imag,
    float* __restrict__ out)
{
    __shared__ __align__(16) _Float16 sA[64][KPAD];  // [a][2n + (0:Re,1:-Im)] of U
    __shared__ __align__(16) _Float16 sB[32][KPAD];  // [b][2n + (0:Re,1: Im)] of V
    __shared__ __align__(16) float    sC[64][CPAD];  // staged output tile

    const int h   = blockIdx.x;
    const int tid = threadIdx.x;
    const int w   = tid >> 6;   // wave 0..7
    const int n   = tid & 63;   // lane = state index n

    // ---- per-n scalar setup (identical across waves; chains differ by w) ----
    {
        const int idx = h * Ndim + n;
        const float dt = __builtin_amdgcn_exp2f(log_dt[h] * LOG2E);
        const float ar = -dt * __builtin_amdgcn_exp2f(inv_A_real[idx] * LOG2E);
        const float ai =  dt * A_imag[idx];
        // scale = dt / (1 - dtA/2)
        const float dre = 1.0f - 0.5f * ar;
        const float dim = -0.5f * ai;
        const float kk  = dt / (dre * dre + dim * dim);
        const float sre =  dre * kk;
        const float sim = -dim * kk;
        // Cm = 2 * B*C*scale (fold final 2x)
        const float br = B_re[idx], bi = B_im[idx];
        const float cr = C_re[idx], ci = C_im[idx];
        const float bcr = br * cr - bi * ci;
        const float bci = br * ci + bi * cr;
        const float cmr = 2.0f * (bcr * sre - bci * sim);
        const float cmi = 2.0f * (bcr * sim + bci * sre);
        // z = exp(dtA)
        const float er = __builtin_amdgcn_exp2f(ar * LOG2E);
        float rev = ai * INV2PI;
        rev -= floorf(rev);
        const float zr = er * __builtin_amdgcn_cosf(rev);
        const float zi = er * __builtin_amdgcn_sinf(rev);
        // power ladder by repeated squaring
        float z4r = zr, z4i = zi;
        cmul(z4r, z4i, z4r, z4i);                       // z^2
        cmul(z4r, z4i, z4r, z4i);                       // z^4
        float z8r = z4r, z8i = z4i;
        cmul(z8r, z8i, z8r, z8i);                       // z^8
        float z16r = z8r, z16i = z8i;
        cmul(z16r, z16i, z16r, z16i);                   // z^16
        float z32r = z16r, z32i = z16i;
        cmul(z32r, z32i, z32r, z32i);                   // z^32
        float z256r = z32r, z256i = z32i;
        cmul(z256r, z256i, z256r, z256i);               // z^64
        cmul(z256r, z256i, z256r, z256i);               // z^128
        cmul(z256r, z256i, z256r, z256i);               // z^256
        float z512r = z256r, z512i = z256i;
        cmul(z512r, z512i, z512r, z512i);               // z^512
        float z1kr = z512r, z1ki = z512i;
        cmul(z1kr, z1ki, z1kr, z1ki);                   // z^1024

        // U chain start: Cm * z^(256w); V chain start: z^(4w)
        float ur = cmr, ui = cmi;
        if (w & 1) cmul(ur, ui, z256r, z256i);
        if (w & 2) cmul(ur, ui, z512r, z512i);
        if (w & 4) cmul(ur, ui, z1kr, z1ki);
        float vr = 1.0f, vi = 0.0f;
        if (w & 1) cmul(vr, vi, z4r, z4i);
        if (w & 2) cmul(vr, vi, z8r, z8i);
        if (w & 4) cmul(vr, vi, z16r, z16i);

        // U-gen: a = 8w + s, step z^32; store {Re, -Im} packed RTZ
#pragma unroll
        for (int s = 0; s < 8; ++s) {
            *(h16x2*)&sA[8 * w + s][2 * n] = __builtin_amdgcn_cvt_pkrtz(ur, -ui);
            cmul(ur, ui, z32r, z32i);
        }
        // V-gen: b = 4w + s, step z; store {Re, Im} packed RTZ
#pragma unroll
        for (int s = 0; s < 4; ++s) {
            *(h16x2*)&sB[4 * w + s][2 * n] = __builtin_amdgcn_cvt_pkrtz(vr, vi);
            cmul(vr, vi, zr, zi);
        }
    }
    __syncthreads();

    // ---- MFMA: wave w owns 16x16 tile (mt = w>>1, nt = w&1), K = 128 ----
    const int mt   = w >> 1;
    const int nt   = w & 1;
    const int mrow = n & 15;
    const int kgrp = n >> 4;
    f32x4 acc = {0.f, 0.f, 0.f, 0.f};
#pragma unroll
    for (int ks = 0; ks < 4; ++ks) {
        const int k0 = ks * 32 + kgrp * 8;              // 8 consecutive k per lane
        const f16x8 af = *(const f16x8*)&sA[16 * mt + mrow][k0];
        const f16x8 bf = *(const f16x8*)&sB[16 * nt + mrow][k0];
        acc = __builtin_amdgcn_mfma_f32_16x16x32_f16(af, bf, acc, 0, 0, 0);
    }

    // ---- stage to LDS (D: col = mrow -> b_local, row = kgrp*4+r -> a_local) ----
#pragma unroll
    for (int r = 0; r < 4; ++r)
        sC[16 * mt + kgrp * 4 + r][16 * nt + mrow] = acc[r];
    __syncthreads();

    // ---- coalesced epilogue: thread tid stores float4 at l = tid*4 ----
    {
        const f32x4 v = *(const f32x4*)&sC[tid >> 3][(tid & 7) * 4];
        *(f32x4*)(out + h * Ldim + tid * 4) = v;
    }
}

extern "C" void kernel_launch(void* const* d_in, const int* in_sizes, int n_in,
                              void* d_out, int out_size, void* d_ws, size_t ws_size,
                              hipStream_t stream) {
    // d_in order: L(scalar), log_dt, C_re, C_im, B_re, B_im, inv_A_real, A_imag
    const float* log_dt     = (const float*)d_in[1];
    const float* C_re       = (const float*)d_in[2];
    const float* C_im       = (const float*)d_in[3];
    const float* B_re       = (const float*)d_in[4];
    const float* B_im       = (const float*)d_in[5];
    const float* inv_A_real = (const float*)d_in[6];
    const float* A_imag     = (const float*)d_in[7];
    float* out = (float*)d_out;

    icmf_mfma<<<Hdim, 512, 0, stream>>>(log_dt, C_re, C_im, B_re, B_im,
                                        inv_A_real, A_imag, out);
}

// Round 10
// 10.492 us; speedup vs baseline: 1.6111x; 1.0174x over previous
//
#include <hip/hip_runtime.h>

// ImplicitComplexModalFilter via single-pass FP16 MFMA factorization.
// K[h, 32a+b] = Re( sum_n U[a,n] * V[n,b] ),  U[a,n] = Cm_n * z_n^(32a) (64x64),
// V[n,b] = z_n^b (64x32), z_n = exp(dtA_n).
// Interleaved-complex K=128 contraction: A[a][2n]=Re U, A[a][2n+1]=-Im U;
// B^T[b][2n]=Re V, B^T[b][2n+1]=Im V  ->  sum_k A B = Re(U V).
// Round 10: kill the repeated-squaring ladder; each wave computes its chain
// anchors (z^(4w), z^(256w)) and steppers (z, z^32) DIRECTLY via exp2/sincos —
// 4 independent short chains instead of one ~25-op serial ladder per thread.

typedef __attribute__((ext_vector_type(8))) _Float16 f16x8;
typedef __attribute__((ext_vector_type(2))) __fp16   h16x2;  // cvt_pkrtz result
typedef __attribute__((ext_vector_type(4))) float    f32x4;

#define Hdim 1024
#define Ndim 64
#define Ldim 2048
#define KPAD 136   // f16 units: 272B row stride, 16B-aligned, conflict-free b128
#define CPAD 36    // f32 units: 144B row stride, 16B-aligned, 2-way alias (free)

#define LOG2E  1.4426950408889634f
#define INV2PI 0.15915494309189535f

__device__ __forceinline__ void cmul(float& xr, float& xi, float yr, float yi) {
    const float tr = fmaf(xr, yr, -(xi * yi));
    xi = fmaf(xr, yi, xi * yr);
    xr = tr;
}

// z^t = exp(dtA * t) from ar2 = Re(dtA)*log2e, airev = Im(dtA)/2pi
__device__ __forceinline__ void expz(float ar2, float airev, float t,
                                     float& zr, float& zi) {
    const float e = __builtin_amdgcn_exp2f(ar2 * t);
    float f = airev * t;
    f -= floorf(f);
    zr = e * __builtin_amdgcn_cosf(f);
    zi = e * __builtin_amdgcn_sinf(f);
}

__global__ __launch_bounds__(512, 8) void icmf_mfma(
    const float* __restrict__ log_dt,
    const float* __restrict__ C_re, const float* __restrict__ C_im,
    const float* __restrict__ B_re, const float* __restrict__ B_im,
    const float* __restrict__ inv_A_real, const float* __restrict__ A_imag,
    float* __restrict__ out)
{
    __shared__ __align__(16) _Float16 sA[64][KPAD];  // [a][2n+(0:Re,1:-Im)] of U
    __shared__ __align__(16) _Float16 sB[32][KPAD];  // [b][2n+(0:Re,1: Im)] of V
    __shared__ __align__(16) float    sC[64][CPAD];  // staged output tile

    const int h   = blockIdx.x;
    const int tid = threadIdx.x;
    const int w   = tid >> 6;   // wave 0..7
    const int n   = tid & 63;   // lane = state index n

    // ---- per-(h,n) setup + per-wave chain anchors (direct evaluation) ----
    {
        const int idx = h * Ndim + n;
        const float dt = __builtin_amdgcn_exp2f(log_dt[h] * LOG2E);
        const float ar = -dt * __builtin_amdgcn_exp2f(inv_A_real[idx] * LOG2E);
        const float ai =  dt * A_imag[idx];
        // scale = dt / (1 - dtA/2)
        const float dre = 1.0f - 0.5f * ar;
        const float dim = -0.5f * ai;
        const float kk  = dt / (dre * dre + dim * dim);
        const float sre =  dre * kk;
        const float sim = -dim * kk;
        // Cm = 2 * B*C*scale (fold final 2x)
        const float br = B_re[idx], bi = B_im[idx];
        const float cr = C_re[idx], ci = C_im[idx];
        const float bcr = br * cr - bi * ci;
        const float bci = br * ci + bi * cr;
        const float cmr = 2.0f * (bcr * sre - bci * sim);
        const float cmi = 2.0f * (bcr * sim + bci * sre);
        const float ar2   = ar * LOG2E;
        const float airev = ai * INV2PI;

        // steppers + anchors: 4 independent direct evaluations
        float z1r, z1i, z32r, z32i, vr, vi, tr_, ti_;
        expz(ar2, airev, 1.0f,              z1r,  z1i);   // V stepper
        expz(ar2, airev, 32.0f,             z32r, z32i);  // U stepper
        expz(ar2, airev, (float)(4 * w),    vr,   vi);    // V start: z^(4w)
        expz(ar2, airev, (float)(256 * w),  tr_,  ti_);   // U start: z^(256w)
        float ur = fmaf(cmr, tr_, -(cmi * ti_));          // u = Cm * z^(256w)
        float ui = fmaf(cmr, ti_,   cmi * tr_);

        // U-gen: a = 8w + s, step z^32; store {Re, -Im} packed RTZ
#pragma unroll
        for (int s = 0; s < 8; ++s) {
            *(h16x2*)&sA[8 * w + s][2 * n] = __builtin_amdgcn_cvt_pkrtz(ur, -ui);
            cmul(ur, ui, z32r, z32i);
        }
        // V-gen: b = 4w + s, step z; store {Re, Im} packed RTZ
#pragma unroll
        for (int s = 0; s < 4; ++s) {
            *(h16x2*)&sB[4 * w + s][2 * n] = __builtin_amdgcn_cvt_pkrtz(vr, vi);
            cmul(vr, vi, z1r, z1i);
        }
    }
    __syncthreads();

    // ---- MFMA: wave w owns 16x16 tile (mt = w>>1, nt = w&1), K = 128 ----
    const int mt   = w >> 1;
    const int nt   = w & 1;
    const int mrow = n & 15;
    const int kgrp = n >> 4;
    f32x4 acc = {0.f, 0.f, 0.f, 0.f};
#pragma unroll
    for (int ks = 0; ks < 4; ++ks) {
        const int k0 = ks * 32 + kgrp * 8;              // 8 consecutive k per lane
        const f16x8 af = *(const f16x8*)&sA[16 * mt + mrow][k0];
        const f16x8 bf = *(const f16x8*)&sB[16 * nt + mrow][k0];
        acc = __builtin_amdgcn_mfma_f32_16x16x32_f16(af, bf, acc, 0, 0, 0);
    }

    // ---- stage to LDS (D: col = mrow -> b_local, row = kgrp*4+r -> a_local) ----
#pragma unroll
    for (int r = 0; r < 4; ++r)
        sC[16 * mt + kgrp * 4 + r][16 * nt + mrow] = acc[r];
    __syncthreads();

    // ---- coalesced epilogue: thread tid stores float4 at l = tid*4 ----
    {
        const f32x4 v = *(const f32x4*)&sC[tid >> 3][(tid & 7) * 4];
        *(f32x4*)(out + h * Ldim + tid * 4) = v;
    }
}

extern "C" void kernel_launch(void* const* d_in, const int* in_sizes, int n_in,
                              void* d_out, int out_size, void* d_ws, size_t ws_size,
                              hipStream_t stream) {
    // d_in order: L(scalar), log_dt, C_re, C_im, B_re, B_im, inv_A_real, A_imag
    const float* log_dt     = (const float*)d_in[1];
    const float* C_re       = (const float*)d_in[2];
    const float* C_im       = (const float*)d_in[3];
    const float* B_re       = (const float*)d_in[4];
    const float* B_im       = (const float*)d_in[5];
    const float* inv_A_real = (const float*)d_in[6];
    const float* A_imag     = (const float*)d_in[7];
    float* out = (float*)d_out;

    icmf_mfma<<<Hdim, 512, 0, stream>>>(log_dt, C_re, C_im, B_re, B_im,
                                        inv_A_real, A_imag, out);
}